// Round 1
// baseline (1295.344 us; speedup 1.0000x reference)
//
#include <hip/hip_runtime.h>
#include <cstdint>
#include <cstddef>

#define NEGV (-1e30f)

constexpr int B_ = 4, C_ = 512, H_ = 128, W_ = 128, MK_ = 128;
constexpr int HW_ = H_ * W_;  // 16384

__device__ inline float bflo(uint32_t u) { union { uint32_t i; float f; } t; t.i = u << 16;          return t.f; }
__device__ inline float bfhi(uint32_t u) { union { uint32_t i; float f; } t; t.i = u & 0xFFFF0000u;  return t.f; }
__device__ inline unsigned short f2bf(float f) {
    union { float f; uint32_t i; } t; t.f = f;
    uint32_t r = t.i + 0x7FFFu + ((t.i >> 16) & 1u);   // RNE
    return (unsigned short)(r >> 16);
}

// out[b][m][p] = sum_c Wmat[m][c]*src[b][c][p]   (+ optional  g*acc + add[b][m][p])
// grid: (HW/256, M/32, B), block 256.
__global__ __launch_bounds__(256) void kgemm(
    const float* __restrict__ Wmat, const float* __restrict__ src,
    float* __restrict__ out, const float* __restrict__ add,
    const float* __restrict__ gammap, int M)
{
    __shared__ __attribute__((aligned(16))) float sX[16 * 256];
    __shared__ __attribute__((aligned(16))) float sW[16 * 32];
    const int tid = threadIdx.x;
    const int pt = blockIdx.x, mt = blockIdx.y, b = blockIdx.z;
    const int lp = tid & 63;       // p lane (4 floats each)
    const int mg = tid >> 6;       // m group (8 m each)

    float acc[8][4];
#pragma unroll
    for (int i = 0; i < 8; i++)
#pragma unroll
        for (int j = 0; j < 4; j++) acc[i][j] = 0.0f;

    for (int c0 = 0; c0 < C_; c0 += 16) {
#pragma unroll
        for (int s = 0; s < 4; s++) {
            const int slot = tid + s * 256;          // 1024 float4 slots
            const int cc = slot >> 6, p4 = slot & 63;
            const float4 v = *(const float4*)(src + ((size_t)(b * C_ + c0 + cc) * HW_ + (size_t)pt * 256 + p4 * 4));
            *(float4*)&sX[cc * 256 + p4 * 4] = v;
        }
#pragma unroll
        for (int s = 0; s < 2; s++) {
            const int slot = tid + s * 256;          // 512 slots
            const int cc = slot >> 5, mi = slot & 31;
            sW[cc * 32 + mi] = Wmat[(size_t)(mt * 32 + mi) * C_ + c0 + cc];
        }
        __syncthreads();
#pragma unroll
        for (int cc = 0; cc < 16; cc++) {
            const float4 xv = *(const float4*)&sX[cc * 256 + lp * 4];
            const float4 w0 = *(const float4*)&sW[cc * 32 + mg * 8];
            const float4 w1 = *(const float4*)&sW[cc * 32 + mg * 8 + 4];
            const float xr[4] = { xv.x, xv.y, xv.z, xv.w };
            const float wr[8] = { w0.x, w0.y, w0.z, w0.w, w1.x, w1.y, w1.z, w1.w };
#pragma unroll
            for (int i = 0; i < 8; i++)
#pragma unroll
                for (int j = 0; j < 4; j++)
                    acc[i][j] = fmaf(wr[i], xr[j], acc[i][j]);
        }
        __syncthreads();
    }

    const float g = gammap ? gammap[0] : 1.0f;
#pragma unroll
    for (int i = 0; i < 8; i++) {
        const int m = mt * 32 + mg * 8 + i;
        const size_t o = ((size_t)b * M + m) * HW_ + (size_t)pt * 256 + lp * 4;
        float4 r = make_float4(acc[i][0], acc[i][1], acc[i][2], acc[i][3]);
        if (add) {
            const float4 a4 = *(const float4*)(add + o);
            r.x = fmaf(g, r.x, a4.x); r.y = fmaf(g, r.y, a4.y);
            r.z = fmaf(g, r.z, a4.z); r.w = fmaf(g, r.w, a4.w);
        }
        *(float4*)(out + o) = r;
    }
}

// dst[map][i][j] (+)= src[map][j][i], maps of 128x128. grid: (16, nmaps), block (32,8)
__global__ __launch_bounds__(256) void ktranspose(
    const float* __restrict__ src, float* __restrict__ dst, int accumulate)
{
    __shared__ float t[32][33];
    const int tx = threadIdx.x, ty = threadIdx.y;
    const int h0 = (blockIdx.x >> 2) * 32, w0 = (blockIdx.x & 3) * 32;
    const size_t base = (size_t)blockIdx.y * HW_;
#pragma unroll
    for (int k = 0; k < 4; k++)
        t[ty + 8 * k][tx] = src[base + (size_t)(h0 + ty + 8 * k) * 128 + w0 + tx];
    __syncthreads();
#pragma unroll
    for (int k = 0; k < 4; k++) {
        const size_t o = base + (size_t)(w0 + ty + 8 * k) * 128 + h0 + tx;
        const float v = t[tx][ty + 8 * k];
        dst[o] = accumulate ? (dst[o] + v) : v;
    }
}

// E[i][j] = sum_{m<64} Q[m][i]*K[m][j];  Q=qkbuf[b][m][s][:], K=qkbuf[b][64+m][s][:]
// writes aout[b][s][i][j]; mask!=0 => diagonal i==j set to NEGV. grid (128, B), block 256
__global__ __launch_bounds__(256) void krowattn(
    const float* __restrict__ qkbuf, float* __restrict__ aout, int mask)
{
    __shared__ __attribute__((aligned(16))) float sQK[128 * 128];   // 64 KB
    const int tid = threadIdx.x;
    const int srow = blockIdx.x, b = blockIdx.y;
    const size_t base_b = (size_t)b * MK_ * H_ * W_;

    for (int s4 = tid; s4 < 4096; s4 += 256) {
        const int mk = s4 >> 5, i4 = s4 & 31;
        const float4 v = *(const float4*)(qkbuf + base_b + ((size_t)mk * H_ + srow) * W_ + i4 * 4);
        *(float4*)&sQK[mk * 128 + i4 * 4] = v;
    }
    __syncthreads();

    const int i0 = (tid >> 4) * 4;
    const int j0 = (tid & 15) * 4;
    float acc[8][8];
#pragma unroll
    for (int a = 0; a < 8; a++)
#pragma unroll
        for (int c = 0; c < 8; c++) acc[a][c] = 0.0f;

    for (int m = 0; m < 64; m++) {
        const float4 qa = *(const float4*)&sQK[m * 128 + i0];
        const float4 qb = *(const float4*)&sQK[m * 128 + i0 + 64];
        const float4 ka = *(const float4*)&sQK[(64 + m) * 128 + j0];
        const float4 kb = *(const float4*)&sQK[(64 + m) * 128 + j0 + 64];
        const float qv[8] = { qa.x, qa.y, qa.z, qa.w, qb.x, qb.y, qb.z, qb.w };
        const float kv[8] = { ka.x, ka.y, ka.z, ka.w, kb.x, kb.y, kb.z, kb.w };
#pragma unroll
        for (int a = 0; a < 8; a++)
#pragma unroll
            for (int c = 0; c < 8; c++)
                acc[a][c] = fmaf(qv[a], kv[c], acc[a][c]);
    }

#pragma unroll
    for (int a = 0; a < 8; a++) {
        const int i = (a < 4) ? (i0 + a) : (i0 + 64 + (a - 4));
        float* dst = aout + ((size_t)(b * H_ + srow) * W_ + i) * 128;
        float4 r0 = make_float4(acc[a][0], acc[a][1], acc[a][2], acc[a][3]);
        float4 r1 = make_float4(acc[a][4], acc[a][5], acc[a][6], acc[a][7]);
        if (mask) {
            const int d0 = i - j0;
            if (d0 >= 0 && d0 < 4) ((float*)&r0)[d0] = NEGV;
            const int d1 = i - (j0 + 64);
            if (d1 >= 0 && d1 < 4) ((float*)&r1)[d1] = NEGV;
        }
        *(float4*)(dst + j0) = r0;
        *(float4*)(dst + j0 + 64) = r1;
    }
}

// joint softmax over 128 row-logits + 128 col-logits per pixel, in place.
// grid 16384, block 256 (4 waves = 4 pixels per block)
__global__ __launch_bounds__(256) void ksoftmax(
    float* __restrict__ aRow, float* __restrict__ aCol)
{
    const int lane = threadIdx.x & 63;
    const int pix = blockIdx.x * 4 + (threadIdx.x >> 6);
    const int b = pix >> 14, rem = pix & 16383;
    const int h = rem >> 7, w = rem & 127;
    float* rp = aRow + ((size_t)(b * 128 + h) * 128 + w) * 128;
    float* cp = aCol + ((size_t)(b * 128 + w) * 128 + h) * 128;
    float2 r = *(float2*)(rp + lane * 2);
    float2 c = *(float2*)(cp + lane * 2);
    float mx = fmaxf(fmaxf(r.x, r.y), fmaxf(c.x, c.y));
#pragma unroll
    for (int off = 32; off > 0; off >>= 1) mx = fmaxf(mx, __shfl_xor(mx, off));
    const float e0 = __expf(r.x - mx), e1 = __expf(r.y - mx);
    const float e2 = __expf(c.x - mx), e3 = __expf(c.y - mx);
    float s = e0 + e1 + e2 + e3;
#pragma unroll
    for (int off = 32; off > 0; off >>= 1) s += __shfl_xor(s, off);
    const float inv = 1.0f / s;
    *(float2*)(rp + lane * 2) = make_float2(e0 * inv, e1 * inv);
    *(float2*)(cp + lane * 2) = make_float2(e2 * inv, e3 * inv);
}

// Y[b][c][s][i] = sum_j A[b][s][i][j] * src[b][c][s][j]   (src/out layout [b][c][128][128])
// grid (128, B), block 256. In-place (out==src) is safe: chunk staged before overwrite.
__global__ __launch_bounds__(256) void kagg(
    const float* __restrict__ src, const float* __restrict__ amat,
    float* __restrict__ out)
{
    __shared__ __attribute__((aligned(16))) unsigned short sA[128 * 132]; // A^T bf16: [j][i]
    __shared__ __attribute__((aligned(16))) unsigned short sX[128 * 68];  // X^T bf16: [j][c_local]
    const int tid = threadIdx.x;
    const int s = blockIdx.x, b = blockIdx.y;
    const float* ap = amat + (size_t)(b * 128 + s) * 16384;

    for (int idx = tid; idx < 4096; idx += 256) {
        const int i = idx >> 5, j4 = idx & 31;
        const float4 v = *(const float4*)(ap + (size_t)i * 128 + j4 * 4);
        sA[(j4 * 4 + 0) * 132 + i] = f2bf(v.x);
        sA[(j4 * 4 + 1) * 132 + i] = f2bf(v.y);
        sA[(j4 * 4 + 2) * 132 + i] = f2bf(v.z);
        sA[(j4 * 4 + 3) * 132 + i] = f2bf(v.w);
    }

    const int cg = tid >> 4;            // 0..15 (4 c each)
    const int i0 = (tid & 15) * 4;      // +64 second block

    for (int c0 = 0; c0 < C_; c0 += 64) {
        __syncthreads();
        for (int idx = tid; idx < 2048; idx += 256) {
            const int cl = idx >> 5, j4 = idx & 31;
            const float4 v = *(const float4*)(src + ((size_t)(b * C_ + c0 + cl) * 128 + s) * 128 + j4 * 4);
            sX[(j4 * 4 + 0) * 68 + cl] = f2bf(v.x);
            sX[(j4 * 4 + 1) * 68 + cl] = f2bf(v.y);
            sX[(j4 * 4 + 2) * 68 + cl] = f2bf(v.z);
            sX[(j4 * 4 + 3) * 68 + cl] = f2bf(v.w);
        }
        __syncthreads();

        float acc[4][8];
#pragma unroll
        for (int c = 0; c < 4; c++)
#pragma unroll
            for (int t = 0; t < 8; t++) acc[c][t] = 0.0f;

        for (int j = 0; j < 128; j++) {
            const uint2 ua = *(const uint2*)&sA[j * 132 + i0];
            const uint2 ub = *(const uint2*)&sA[j * 132 + i0 + 64];
            const uint2 ux = *(const uint2*)&sX[j * 68 + cg * 4];
            const float av[8] = { bflo(ua.x), bfhi(ua.x), bflo(ua.y), bfhi(ua.y),
                                  bflo(ub.x), bfhi(ub.x), bflo(ub.y), bfhi(ub.y) };
            const float xr[4] = { bflo(ux.x), bfhi(ux.x), bflo(ux.y), bfhi(ux.y) };
#pragma unroll
            for (int c = 0; c < 4; c++)
#pragma unroll
                for (int t = 0; t < 8; t++)
                    acc[c][t] = fmaf(xr[c], av[t], acc[c][t]);
        }

#pragma unroll
        for (int cl = 0; cl < 4; cl++) {
            const int c = c0 + cg * 4 + cl;
            float* op = out + ((size_t)(b * C_ + c) * 128 + s) * 128;
            *(float4*)(op + i0)      = make_float4(acc[cl][0], acc[cl][1], acc[cl][2], acc[cl][3]);
            *(float4*)(op + i0 + 64) = make_float4(acc[cl][4], acc[cl][5], acc[cl][6], acc[cl][7]);
        }
    }
}

extern "C" void kernel_launch(void* const* d_in, const int* in_sizes, int n_in,
                              void* d_out, int out_size, void* d_ws, size_t ws_size,
                              hipStream_t stream) {
    const float* x     = (const float*)d_in[0];
    const float* Wq    = (const float*)d_in[1];
    const float* Wk    = (const float*)d_in[2];
    const float* Wv    = (const float*)d_in[3];
    const float* gamma = (const float*)d_in[4];
    float* out = (float*)d_out;
    float* ws  = (float*)d_ws;

    // workspace layout (floats); total 92,340,224 floats = ~352 MiB
    float* Wqk  = ws;                       //    65,536
    float* qk   = Wqk + 65536;              // 8,388,608  [b][mk][h][w]
    float* aCol = qk;                       // alias: qk dead after krowattn(row) reads + transpose
    float* qkT  = qk + 8388608;             // 8,388,608  [b][mk][w][h]
    float* aRow = qkT + 8388608;            // 8,388,608  [b][h][w][j]
    float* yRow = aRow + 8388608;           // 33,554,432 [b][c][h][w]
    float* xT   = yRow + 33554432;          // 33,554,432 [b][c][w][h]; then yColT in-place

    hipMemcpyAsync(Wqk,             Wq, 64 * 512 * sizeof(float), hipMemcpyDeviceToDevice, stream);
    hipMemcpyAsync(Wqk + 64 * 512,  Wk, 64 * 512 * sizeof(float), hipMemcpyDeviceToDevice, stream);

    // 1. qk = Wqk @ x   (per batch, M=128)
    kgemm<<<dim3(64, 4, 4), 256, 0, stream>>>(Wqk, x, qk, nullptr, nullptr, 128);
    // 2. qkT
    ktranspose<<<dim3(16, 512), dim3(32, 8), 0, stream>>>(qk, qkT, 0);
    // 3. row logits (eW, unmasked) -> aRow[b][h][w][j]
    krowattn<<<dim3(128, 4), 256, 0, stream>>>(qk, aRow, 0);
    // 4. col logits (eH, diag mask) -> aCol[b][w][h][j]   (overwrites qk space)
    krowattn<<<dim3(128, 4), 256, 0, stream>>>(qkT, aCol, 1);
    // 5. joint softmax in place
    ksoftmax<<<dim3(16384), 256, 0, stream>>>(aRow, aCol);
    // 6. row aggregation: yRow[b][c][h][w] = sum_j aRow[b][h][w][j] x[b][c][h][j]
    kagg<<<dim3(128, 4), 256, 0, stream>>>(x, aRow, yRow);
    // 7. xT
    ktranspose<<<dim3(16, 2048), dim3(32, 8), 0, stream>>>(x, xT, 0);
    // 8. col aggregation (in place over xT): yColT[b][c][w][h] = sum_j aCol[b][w][h][j] xT[b][c][w][j]
    kagg<<<dim3(128, 4), 256, 0, stream>>>(xT, aCol, xT);
    // 9. yRow += T(yColT)
    ktranspose<<<dim3(16, 2048), dim3(32, 8), 0, stream>>>(xT, yRow, 1);
    // 10. out = gamma * (Wv @ yRow) + x
    kgemm<<<dim3(64, 16, 4), 256, 0, stream>>>(Wv, yRow, out, x, gamma, 512);
}

// Round 2
// 554.303 us; speedup vs baseline: 2.3369x; 2.3369x over previous
//
#include <hip/hip_runtime.h>
#include <cstdint>
#include <cstddef>

#define NEGV (-1e30f)

constexpr int C_ = 512, H_ = 128, W_ = 128;
constexpr int P_ = 16384;   // H*W

typedef short bf16x8 __attribute__((ext_vector_type(8)));
typedef float f32x4  __attribute__((ext_vector_type(4)));
#define MFMA16(a, b, c) __builtin_amdgcn_mfma_f32_16x16x32_bf16((a), (b), (c), 0, 0, 0)

__device__ inline unsigned short f2bf(float f) {
    union { float f; uint32_t i; } t; t.f = f;
    uint32_t r = t.i + 0x7FFFu + ((t.i >> 16) & 1u);   // RNE
    return (unsigned short)(r >> 16);
}
__device__ inline float bf2f(unsigned short u) {
    union { uint32_t i; float f; } t; t.i = (uint32_t)u << 16; return t.f;
}

// ---------------------------------------------------------------------------
// Weight conversion: Wq,Wk -> Wqkbf[128][512] (q rows 0..63, k rows 64..127);
// Wv -> Wvbf[512][512]. 4 elems/thread.
__global__ __launch_bounds__(256) void kwconv(
    const float* __restrict__ Wq, const float* __restrict__ Wk,
    const float* __restrict__ Wv,
    unsigned short* __restrict__ Wqkbf, unsigned short* __restrict__ Wvbf)
{
    const int i4 = (blockIdx.x * 256 + threadIdx.x) * 4;
    const float* src; unsigned short* dst; int off;
    if (i4 < 32768)       { src = Wq + i4;          dst = Wqkbf + i4; }
    else if (i4 < 65536)  { off = i4 - 32768; src = Wk + off; dst = Wqkbf + i4; }
    else                  { off = i4 - 65536; src = Wv + off; dst = Wvbf + off; }
    const float4 v = *(const float4*)src;
    ushort4 u; u.x = f2bf(v.x); u.y = f2bf(v.y); u.z = f2bf(v.z); u.w = f2bf(v.w);
    *(ushort4*)dst = u;
}

// ---------------------------------------------------------------------------
// x[b][c][h][w] fp32 -> xTbf[b][c][w][h] bf16 (per-map 128x128 transpose)
__global__ __launch_bounds__(256) void kprep1(
    const float* __restrict__ x, unsigned short* __restrict__ xTbf)
{
    __shared__ float t[32][33];
    const int tx = threadIdx.x, ty = threadIdx.y;
    const int h0 = (blockIdx.x >> 2) * 32, w0 = (blockIdx.x & 3) * 32;
    const size_t base = (size_t)blockIdx.y * P_;
#pragma unroll
    for (int k = 0; k < 4; k++)
        t[ty + 8 * k][tx] = x[base + (size_t)(h0 + ty + 8 * k) * 128 + w0 + tx];
    __syncthreads();
#pragma unroll
    for (int k = 0; k < 4; k++)
        xTbf[base + (size_t)(w0 + ty + 8 * k) * 128 + h0 + tx] = f2bf(t[tx][ty + 8 * k]);
}

// x[b][c][p] fp32 -> xbfT[b][p][c] bf16  (c <-> p transpose), tiles 32c x 32p
__global__ __launch_bounds__(256) void kprep2(
    const float* __restrict__ x, unsigned short* __restrict__ xbfT)
{
    __shared__ float t[32][33];
    const int tx = threadIdx.x, ty = threadIdx.y;
    const int p0 = blockIdx.x * 32, c0 = blockIdx.y * 32, b = blockIdx.z;
#pragma unroll
    for (int k = 0; k < 4; k++)
        t[ty + 8 * k][tx] = x[((size_t)(b * C_ + c0 + ty + 8 * k)) * P_ + p0 + tx];
    __syncthreads();
#pragma unroll
    for (int k = 0; k < 4; k++)
        xbfT[((size_t)b * P_ + p0 + ty + 8 * k) * C_ + c0 + tx] = f2bf(t[tx][ty + 8 * k]);
}

// ---------------------------------------------------------------------------
// MFMA GEMM, K=512. D[m][n=p] = sum_c A[m][c] * Bm[p][c].
// A row-major [M][512] bf16; Bm [b][p][512] bf16 (p-major).
// mode qk (outbf): store bf16 at qkP[b][p][mk]  (mk = row index m)
// mode final (outf): out[b][m][p] = gamma*acc + addx[same], fp32
__global__ __launch_bounds__(256) void kgemm_mfma(
    const unsigned short* __restrict__ A, const unsigned short* __restrict__ Bm,
    unsigned short* __restrict__ outbf, float* __restrict__ outf,
    const float* __restrict__ addx, const float* __restrict__ gammap)
{
    __shared__ __attribute__((aligned(16))) unsigned short sA[128 * 72];
    __shared__ __attribute__((aligned(16))) unsigned short sB[128 * 72];
    const int tid = threadIdx.x;
    const int pbase = blockIdx.x * 128, mt = blockIdx.y, b = blockIdx.z;
    const int lane = tid & 63, wv = tid >> 6;
    const int m0 = (wv >> 1) * 64, p0 = (wv & 1) * 64;
    const int fr = lane & 15, fq = lane >> 4;

    f32x4 acc[4][4];
#pragma unroll
    for (int i = 0; i < 4; i++)
#pragma unroll
        for (int j = 0; j < 4; j++) acc[i][j] = (f32x4){0.f, 0.f, 0.f, 0.f};

    const size_t arow0 = (size_t)(mt * 128) * 512;
    const size_t brow0 = ((size_t)b * P_ + pbase) * 512;

    for (int kc = 0; kc < 512; kc += 64) {
#pragma unroll
        for (int rep = 0; rep < 4; rep++) {
            const int idx = rep * 256 + tid;
            const int kg = idx & 7, r = idx >> 3;
            *(uint4*)&sA[r * 72 + kg * 8] = *(const uint4*)&A[arow0 + (size_t)r * 512 + kc + kg * 8];
            *(uint4*)&sB[r * 72 + kg * 8] = *(const uint4*)&Bm[brow0 + (size_t)r * 512 + kc + kg * 8];
        }
        __syncthreads();
#pragma unroll
        for (int kk = 0; kk < 64; kk += 32) {
            bf16x8 af[4], bfv[4];
#pragma unroll
            for (int t = 0; t < 4; t++) af[t]  = *(const bf16x8*)&sA[(m0 + t * 16 + fr) * 72 + kk + fq * 8];
#pragma unroll
            for (int t = 0; t < 4; t++) bfv[t] = *(const bf16x8*)&sB[(p0 + t * 16 + fr) * 72 + kk + fq * 8];
#pragma unroll
            for (int i = 0; i < 4; i++)
#pragma unroll
                for (int j = 0; j < 4; j++)
                    acc[i][j] = MFMA16(af[i], bfv[j], acc[i][j]);
        }
        __syncthreads();
    }

    if (outbf) {
        // qkP[b][p][mk] bf16, pack 4 consecutive mk (quad*4+r) per store
#pragma unroll
        for (int tj = 0; tj < 4; tj++) {
            const int p_g = pbase + p0 + tj * 16 + fr;
            const size_t rowo = ((size_t)b * P_ + p_g) * 128;
#pragma unroll
            for (int ti = 0; ti < 4; ti++) {
                const int mk = m0 + ti * 16 + fq * 4;
                ushort4 u;
                u.x = f2bf(acc[ti][tj][0]); u.y = f2bf(acc[ti][tj][1]);
                u.z = f2bf(acc[ti][tj][2]); u.w = f2bf(acc[ti][tj][3]);
                *(ushort4*)&outbf[rowo + mk] = u;
            }
        }
    } else {
        const float g = gammap[0];
#pragma unroll
        for (int ti = 0; ti < 4; ti++)
#pragma unroll
            for (int r = 0; r < 4; r++) {
                const int m_g = mt * 128 + m0 + ti * 16 + fq * 4 + r;
                const size_t rowo = ((size_t)(b * 512 + m_g)) * P_;
#pragma unroll
                for (int tj = 0; tj < 4; tj++) {
                    const int p_g = pbase + p0 + tj * 16 + fr;
                    outf[rowo + p_g] = fmaf(g, acc[ti][tj][r], addx[rowo + p_g]);
                }
            }
    }
}

// ---------------------------------------------------------------------------
// Logits: per (b, s): E[i][j] = sum_{m<64} Q[m][i]*K[m][j], Q/K from qkP[b][p][mk]
// row variant: p(i) = s*128 + i    (rowMul=128, rowStep=1)
// col variant: p(i) = i*128 + s    (rowMul=1,  rowStep=128), diag mask
__global__ __launch_bounds__(256) void klogits(
    const unsigned short* __restrict__ qkP, float* __restrict__ E,
    int rowMul, int rowStep, int mask)
{
    __shared__ __attribute__((aligned(16))) unsigned short sPM[128 * 136];
    const int tid = threadIdx.x;
    const int s = blockIdx.x, b = blockIdx.y;
    const size_t qbase = (size_t)b * P_ * 128;
    const int rb = s * rowMul;
#pragma unroll
    for (int rep = 0; rep < 8; rep++) {
        const int idx = rep * 256 + tid;
        const int mkg = idx & 15, i = idx >> 4;
        *(uint4*)&sPM[i * 136 + mkg * 8] =
            *(const uint4*)&qkP[qbase + (size_t)(rb + i * rowStep) * 128 + mkg * 8];
    }
    __syncthreads();

    const int lane = tid & 63, wv = tid >> 6;
    const int i0 = (wv >> 1) * 64, j0 = (wv & 1) * 64;
    const int fr = lane & 15, fq = lane >> 4;

    f32x4 acc[4][4];
#pragma unroll
    for (int i = 0; i < 4; i++)
#pragma unroll
        for (int j = 0; j < 4; j++) acc[i][j] = (f32x4){0.f, 0.f, 0.f, 0.f};

#pragma unroll
    for (int kk = 0; kk < 64; kk += 32) {
        bf16x8 af[4], bfv[4];
#pragma unroll
        for (int t = 0; t < 4; t++) af[t]  = *(const bf16x8*)&sPM[(i0 + t * 16 + fr) * 136 + kk + fq * 8];
#pragma unroll
        for (int t = 0; t < 4; t++) bfv[t] = *(const bf16x8*)&sPM[(j0 + t * 16 + fr) * 136 + 64 + kk + fq * 8];
#pragma unroll
        for (int i = 0; i < 4; i++)
#pragma unroll
            for (int j = 0; j < 4; j++)
                acc[i][j] = MFMA16(af[i], bfv[j], acc[i][j]);
    }

    float* Eb = E + ((size_t)(b * 128 + s)) * P_;
#pragma unroll
    for (int ti = 0; ti < 4; ti++)
#pragma unroll
        for (int r = 0; r < 4; r++) {
            const int i_g = i0 + ti * 16 + fq * 4 + r;
#pragma unroll
            for (int tj = 0; tj < 4; tj++) {
                const int j_g = j0 + tj * 16 + fr;
                float v = acc[ti][tj][r];
                if (mask && i_g == j_g) v = NEGV;
                Eb[(size_t)i_g * 128 + j_g] = v;
            }
        }
}

// ---------------------------------------------------------------------------
// Joint softmax over 128 row + 128 col logits per pixel; fp32 in, bf16 out.
__global__ __launch_bounds__(256) void ksoftmax(
    const float* __restrict__ ER, const float* __restrict__ EC,
    unsigned short* __restrict__ AR, unsigned short* __restrict__ AC)
{
    const int lane = threadIdx.x & 63;
    const int pix = blockIdx.x * 4 + (threadIdx.x >> 6);
    const int b = pix >> 14, rem = pix & 16383;
    const int h = rem >> 7, w = rem & 127;
    const size_t ro = ((size_t)((b * 128 + h) * 128 + w)) * 128;
    const size_t co = ((size_t)((b * 128 + w) * 128 + h)) * 128;
    const float2 r = *(const float2*)(ER + ro + lane * 2);
    const float2 c = *(const float2*)(EC + co + lane * 2);
    float mx = fmaxf(fmaxf(r.x, r.y), fmaxf(c.x, c.y));
#pragma unroll
    for (int off = 32; off > 0; off >>= 1) mx = fmaxf(mx, __shfl_xor(mx, off));
    const float e0 = __expf(r.x - mx), e1 = __expf(r.y - mx);
    const float e2 = __expf(c.x - mx), e3 = __expf(c.y - mx);
    float sm = e0 + e1 + e2 + e3;
#pragma unroll
    for (int off = 32; off > 0; off >>= 1) sm += __shfl_xor(sm, off);
    const float inv = 1.0f / sm;
    ushort2 u0; u0.x = f2bf(e0 * inv); u0.y = f2bf(e1 * inv);
    ushort2 u1; u1.x = f2bf(e2 * inv); u1.y = f2bf(e3 * inv);
    *(ushort2*)(AR + ro + lane * 2) = u0;
    *(ushort2*)(AC + co + lane * 2) = u1;
}

// ---------------------------------------------------------------------------
// Aggregation as D[m=i][n=c] = sum_j Attn[i][j] * X[c][j], written to
// ySumT[b][p][c] bf16 with p = s*pMul + i*pStep. rmw: += existing.
// Row: X from fp32 x (rows [c][s*128+j]); Col: X from bf16 xTbf.
__global__ __launch_bounds__(256) void kagg(
    const unsigned short* __restrict__ At, const float* __restrict__ Xf,
    const unsigned short* __restrict__ Xbf, unsigned short* __restrict__ ySumT,
    int pMul, int pStep, int rmw)
{
    __shared__ __attribute__((aligned(16))) unsigned short sA[128 * 72];
    __shared__ __attribute__((aligned(16))) unsigned short sB[128 * 72];
    const int tid = threadIdx.x;
    const int s = blockIdx.x, b = blockIdx.y, ct = blockIdx.z;
    const int lane = tid & 63, wv = tid >> 6;
    const int m0 = (wv >> 1) * 64, n0 = (wv & 1) * 64;
    const int fr = lane & 15, fq = lane >> 4;
    const size_t abase = ((size_t)(b * 128 + s)) * P_;

    f32x4 acc[4][4];
#pragma unroll
    for (int i = 0; i < 4; i++)
#pragma unroll
        for (int j = 0; j < 4; j++) acc[i][j] = (f32x4){0.f, 0.f, 0.f, 0.f};

    for (int kc = 0; kc < 128; kc += 64) {
#pragma unroll
        for (int rep = 0; rep < 4; rep++) {
            const int idx = rep * 256 + tid;
            const int jg = idx & 7, i = idx >> 3;
            *(uint4*)&sA[i * 72 + jg * 8] = *(const uint4*)&At[abase + (size_t)i * 128 + kc + jg * 8];
        }
        if (Xf) {
#pragma unroll
            for (int rep = 0; rep < 8; rep++) {
                const int idx = rep * 256 + tid;
                const int jq = idx & 15, cc = idx >> 4;
                const float4 v = *(const float4*)&Xf[((size_t)(b * C_ + ct * 128 + cc)) * P_ + s * 128 + kc + jq * 4];
                ushort4 u; u.x = f2bf(v.x); u.y = f2bf(v.y); u.z = f2bf(v.z); u.w = f2bf(v.w);
                *(ushort4*)&sB[cc * 72 + jq * 4] = u;
            }
        } else {
#pragma unroll
            for (int rep = 0; rep < 4; rep++) {
                const int idx = rep * 256 + tid;
                const int jg = idx & 7, cc = idx >> 3;
                *(uint4*)&sB[cc * 72 + jg * 8] =
                    *(const uint4*)&Xbf[((size_t)(b * C_ + ct * 128 + cc)) * P_ + s * 128 + kc + jg * 8];
            }
        }
        __syncthreads();
#pragma unroll
        for (int kk = 0; kk < 64; kk += 32) {
            bf16x8 af[4], bfv[4];
#pragma unroll
            for (int t = 0; t < 4; t++) af[t]  = *(const bf16x8*)&sA[(m0 + t * 16 + fr) * 72 + kk + fq * 8];
#pragma unroll
            for (int t = 0; t < 4; t++) bfv[t] = *(const bf16x8*)&sB[(n0 + t * 16 + fr) * 72 + kk + fq * 8];
#pragma unroll
            for (int i = 0; i < 4; i++)
#pragma unroll
                for (int j = 0; j < 4; j++)
                    acc[i][j] = MFMA16(af[i], bfv[j], acc[i][j]);
        }
        __syncthreads();
    }

#pragma unroll
    for (int ti = 0; ti < 4; ti++)
#pragma unroll
        for (int r = 0; r < 4; r++) {
            const int i_g = m0 + ti * 16 + fq * 4 + r;
            const size_t p = (size_t)s * pMul + (size_t)i_g * pStep;
            const size_t rowo = ((size_t)b * P_ + p) * 512;
#pragma unroll
            for (int tc = 0; tc < 4; tc++) {
                const int c_g = ct * 128 + n0 + tc * 16 + fr;
                float v = acc[ti][tc][r];
                if (rmw) v += bf2f(ySumT[rowo + c_g]);
                ySumT[rowo + c_g] = f2bf(v);
            }
        }
}

// ---------------------------------------------------------------------------
extern "C" void kernel_launch(void* const* d_in, const int* in_sizes, int n_in,
                              void* d_out, int out_size, void* d_ws, size_t ws_size,
                              hipStream_t stream) {
    const float* x     = (const float*)d_in[0];
    const float* Wq    = (const float*)d_in[1];
    const float* Wk    = (const float*)d_in[2];
    const float* Wv    = (const float*)d_in[3];
    const float* gamma = (const float*)d_in[4];
    float* out = (float*)d_out;

    char* base = (char*)d_ws;
    unsigned short* Wqkbf = (unsigned short*)base;             base += 131072;      // 128x512
    unsigned short* Wvbf  = (unsigned short*)base;             base += 524288;      // 512x512
    unsigned short* xTbf  = (unsigned short*)base;             base += 67108864;    // [b][c][w][h]
    unsigned short* xbfT  = (unsigned short*)base;             base += 67108864;    // [b][p][c]
    unsigned short* qkP   = (unsigned short*)base;             base += 16777216;    // [b][p][mk]
    float*          ERow  = (float*)base;                      base += 33554432;    // [b][h][i][j]
    float*          ECol  = (float*)base;                      base += 33554432;    // [b][w][i][j]
    unsigned short* ARow  = (unsigned short*)base;             base += 16777216;
    unsigned short* ACol  = (unsigned short*)base;             base += 16777216;
    unsigned short* ySumT = (unsigned short*)base;             base += 67108864;    // [b][p][c]

    kwconv<<<320, 256, 0, stream>>>(Wq, Wk, Wv, Wqkbf, Wvbf);
    kprep1<<<dim3(16, 2048), dim3(32, 8), 0, stream>>>(x, xTbf);
    kprep2<<<dim3(512, 16, 4), dim3(32, 8), 0, stream>>>(x, xbfT);
    // qk[b][p][mk] = Wqk @ x
    kgemm_mfma<<<dim3(128, 1, 4), 256, 0, stream>>>(Wqkbf, xbfT, qkP, nullptr, nullptr, nullptr);
    // row logits (eW): per (b,h), p(i)=h*128+i
    klogits<<<dim3(128, 4), 256, 0, stream>>>(qkP, ERow, 128, 1, 0);
    // col logits (eH): per (b,w), p(i)=i*128+w, diagonal mask
    klogits<<<dim3(128, 4), 256, 0, stream>>>(qkP, ECol, 1, 128, 1);
    ksoftmax<<<16384, 256, 0, stream>>>(ERow, ECol, ARow, ACol);
    // row agg: ySumT[(h,i)][c] = sum_j ARow[h][i][j] * x[c][h*128+j]
    kagg<<<dim3(128, 4, 4), 256, 0, stream>>>(ARow, x, nullptr, ySumT, 128, 1, 0);
    // col agg: ySumT[(i,w)][c] += sum_j ACol[w][i][j] * xT[c][w*128+j]
    kagg<<<dim3(128, 4, 4), 256, 0, stream>>>(ACol, nullptr, xTbf, ySumT, 1, 128, 1);
    // out = gamma * (Wv @ ySum) + x
    kgemm_mfma<<<dim3(128, 4, 4), 256, 0, stream>>>(Wvbf, ySumT, nullptr, out, x, gamma);
}